// Round 1
// baseline (5349.373 us; speedup 1.0000x reference)
//
#include <hip/hip_runtime.h>
#include <cstdint>

#define B 16
#define TY 1600
#define TX 400
#define MAS 384
#define HID 768
#define NEGV -1e9f

// ---------------- generic transpose: out[r*C + c] = in[c*R + r] ----------------
__global__ void transpose_k(const float* __restrict__ in, float* __restrict__ out, int C, int R) {
  int idx = blockIdx.x * 256 + threadIdx.x;
  if (idx >= C * R) return;
  int r = idx / C, c = idx - r * C;
  out[idx] = in[(size_t)c * R + r];
}

// ---------------- conv1 + ReGLU: x[B,T,CIN] -> h[B,T,768] ----------------
// wr: repacked [CIN*K][1536] (a-cols 0..767, g-cols 768..1535)
template<int CIN, int K, int T>
__global__ __launch_bounds__(256)
void conv_glu_k(const float* __restrict__ x, const float* __restrict__ wr,
                const float* __restrict__ bias, const int* __restrict__ lens,
                float* __restrict__ h)
{
  constexpr int TT = 16, PAD = K / 2, ROWS = TT + K - 1;
  __shared__ float xs[ROWS * CIN];
  const int b = blockIdx.y, t0 = blockIdx.x * TT, tid = threadIdx.x;
  const int len = lens[b];
  for (int e = tid; e < ROWS * CIN; e += 256) {
    int row = e / CIN, ci = e - row * CIN;
    int t = t0 + row - PAD;
    xs[e] = (t >= 0 && t < len) ? x[((size_t)b * T + t) * CIN + ci] : 0.f;
  }
  __syncthreads();
  float aa0[TT] = {}, aa1[TT] = {}, aa2[TT] = {};
  float gg0[TT] = {}, gg1[TT] = {}, gg2[TT] = {};
  for (int ci = 0; ci < CIN; ++ci) {
    #pragma unroll
    for (int k = 0; k < K; ++k) {
      const float* wrow = wr + (size_t)(ci * K + k) * 1536;
      float wa0 = wrow[tid], wa1 = wrow[tid + 256], wa2 = wrow[tid + 512];
      float wg0 = wrow[tid + 768], wg1 = wrow[tid + 1024], wg2 = wrow[tid + 1280];
      #pragma unroll
      for (int t = 0; t < TT; ++t) {
        float xv = xs[(t + k) * CIN + ci];
        aa0[t] = fmaf(xv, wa0, aa0[t]); aa1[t] = fmaf(xv, wa1, aa1[t]); aa2[t] = fmaf(xv, wa2, aa2[t]);
        gg0[t] = fmaf(xv, wg0, gg0[t]); gg1[t] = fmaf(xv, wg1, gg1[t]); gg2[t] = fmaf(xv, wg2, gg2[t]);
      }
    }
  }
  #pragma unroll
  for (int t = 0; t < TT; ++t) {
    int tt = t0 + t;
    if (tt < T) {
      bool keep = tt < len;
      size_t o = ((size_t)b * T + tt) * HID;
      float a0 = aa0[t] + bias[tid],       g0 = gg0[t] + bias[tid + 768];
      float a1 = aa1[t] + bias[tid + 256], g1 = gg1[t] + bias[tid + 1024];
      float a2 = aa2[t] + bias[tid + 512], g2 = gg2[t] + bias[tid + 1280];
      h[o + tid]       = keep ? a0 * fmaxf(g0, 0.f) : 0.f;
      h[o + tid + 256] = keep ? a1 * fmaxf(g1, 0.f) : 0.f;
      h[o + tid + 512] = keep ? a2 * fmaxf(g2, 0.f) : 0.f;
    }
  }
}

// ---------------- conv2 / linear: x[B,T,CIN] -> out[B,T,384] (or transposed [B,384,T]) ----------------
// wr: repacked [CIN*K][384]
template<int CIN, int K, int T, bool MASK, bool STORET>
__global__ __launch_bounds__(192)
void conv2_k(const float* __restrict__ x, const float* __restrict__ wr,
             const float* __restrict__ bias, const int* __restrict__ lens,
             float* __restrict__ out)
{
  constexpr int TT = 48, CICH = 96, PAD = K / 2, ROWS = TT + K - 1;
  __shared__ float xs[ROWS * CICH];
  const int b = blockIdx.y, t0 = blockIdx.x * TT, tid = threadIdx.x;
  const int len = lens[b];
  const int c0 = tid, c1 = tid + 192;
  float acc0[TT] = {}, acc1[TT] = {};
  for (int ci0 = 0; ci0 < CIN; ci0 += CICH) {
    __syncthreads();
    for (int e = tid; e < ROWS * CICH; e += 192) {
      int row = e / CICH, ci = e - row * CICH;
      int t = t0 + row - PAD;
      xs[e] = (t >= 0 && t < len) ? x[((size_t)b * T + t) * CIN + ci0 + ci] : 0.f;
    }
    __syncthreads();
    for (int ci = 0; ci < CICH; ++ci) {
      #pragma unroll
      for (int k = 0; k < K; ++k) {
        const float* wrow = wr + (size_t)((ci0 + ci) * K + k) * MAS;
        float w0 = wrow[c0], w1 = wrow[c1];
        #pragma unroll
        for (int t = 0; t < TT; ++t) {
          float xv = xs[(t + k) * CICH + ci];
          acc0[t] = fmaf(xv, w0, acc0[t]);
          acc1[t] = fmaf(xv, w1, acc1[t]);
        }
      }
    }
  }
  const float b0 = bias[c0], b1 = bias[c1];
  #pragma unroll
  for (int t = 0; t < TT; ++t) {
    int tt = t0 + t;
    if (tt < T) {
      float v0 = acc0[t] + b0, v1 = acc1[t] + b1;
      if (MASK && tt >= len) { v0 = 0.f; v1 = 0.f; }
      if (STORET) {
        out[((size_t)b * MAS + c0) * T + tt] = v0;
        out[((size_t)b * MAS + c1) * T + tt] = v1;
      } else {
        size_t o = ((size_t)b * T + tt) * MAS;
        out[o + c0] = v0; out[o + c1] = v1;
      }
    }
  }
}

// ---------------- scores + softmax + safe_log ----------------
// q[B,TY,384], kT[B,384,TX] -> avg_attn[B,TY,TX], logprob[B,TY,TX]
__global__ __launch_bounds__(512)
void scores_k(const float* __restrict__ q, const float* __restrict__ kT,
              const int* __restrict__ xl, const int* __restrict__ yl,
              float* __restrict__ oattn, float* __restrict__ ologp)
{
  __shared__ float qs[16 * 384];
  __shared__ float tmp[8];
  const int b = blockIdx.y, y0 = blockIdx.x * 16, tid = threadIdx.x;
  for (int e = tid; e < 16 * 384; e += 512)
    qs[e] = q[((size_t)b * TY + (y0 + e / 384)) * 384 + (e - (e / 384) * 384)];
  __syncthreads();
  float acc[16];
  #pragma unroll
  for (int i = 0; i < 16; ++i) acc[i] = 0.f;
  const int x = tid;
  if (x < TX) {
    const float* kb = kT + (size_t)b * MAS * TX + x;
    for (int d = 0; d < 384; d += 4) {
      float k0 = kb[(size_t)(d + 0) * TX], k1 = kb[(size_t)(d + 1) * TX];
      float k2 = kb[(size_t)(d + 2) * TX], k3 = kb[(size_t)(d + 3) * TX];
      #pragma unroll
      for (int yy = 0; yy < 16; ++yy) {
        float4 qv = *(const float4*)&qs[yy * 384 + d];
        acc[yy] = fmaf(qv.x, k0, fmaf(qv.y, k1, fmaf(qv.z, k2, fmaf(qv.w, k3, acc[yy]))));
      }
    }
  }
  const int xlen = xl[b], ylen = yl[b];
  const float scale = 0.05103103630798288f;  // 1/sqrt(384)
  const bool xpad = (x >= xlen);
  const int wv = tid >> 6, ln = tid & 63;
  #pragma unroll 1
  for (int yy = 0; yy < 16; ++yy) {
    int y = y0 + yy;
    float s = -3.0e38f;
    if (x < TX) {
      s = acc[yy] * scale;
      if (xpad && (y >= ylen)) s = -1e-9f;
    }
    float m = s;
    for (int off = 32; off; off >>= 1) m = fmaxf(m, __shfl_xor(m, off));
    if (ln == 0) tmp[wv] = m;
    __syncthreads();
    float mx = fmaxf(fmaxf(fmaxf(tmp[0], tmp[1]), fmaxf(tmp[2], tmp[3])),
                     fmaxf(fmaxf(tmp[4], tmp[5]), fmaxf(tmp[6], tmp[7])));
    __syncthreads();
    float e = (x < TX) ? expf(s - mx) : 0.f;
    float sm = e;
    for (int off = 32; off; off >>= 1) sm += __shfl_xor(sm, off);
    if (ln == 0) tmp[wv] = sm;
    __syncthreads();
    float tot = tmp[0] + tmp[1] + tmp[2] + tmp[3] + tmp[4] + tmp[5] + tmp[6] + tmp[7];
    __syncthreads();
    if (x < TX) {
      float w = e / tot;
      size_t o = ((size_t)b * TY + y) * TX + x;
      oattn[o] = w;
      ologp[o] = logf(w + 1e-6f);
    }
  }
}

// ---------------- MAS: forward DP (1 wave/batch) + bit-recorded backtrack ----------------
// lane l owns x in [7l, 7l+7); bits[b][y][lane] bit j = (v[y-1][x-1] > v[y-1][x]) for x=7l+j
__global__ __launch_bounds__(64)
void mas_k(const float* __restrict__ logprob, const int* __restrict__ xl, const int* __restrict__ yl,
           unsigned char* __restrict__ bits, float* __restrict__ hard, float* __restrict__ dur)
{
  const int b = blockIdx.x;
  const int lane = threadIdx.x;
  const int xlen = xl[b], ylen = yl[b];
  const int xbase = lane * 7;
  float prev[7];
  #pragma unroll
  for (int j = 0; j < 7; ++j) prev[j] = (xbase + j == 0) ? 0.f : NEGV;
  const float* lpb = logprob + (size_t)b * TY * TX;
  unsigned char* bb = bits + (size_t)b * TY * 64;
  for (int y = 0; y < TY; ++y) {
    float left = __shfl_up(prev[6], 1);  // lane l gets lane l-1's prev[6] (x = 7l - 1)
    const float* row = lpb + (size_t)y * TX;
    unsigned byte = 0;
    float cur[7];
    #pragma unroll
    for (int j = 0; j < 7; ++j) {
      int x = xbase + j;
      float pl  = (j == 0) ? left : prev[j - 1];
      float plm = (x == 0) ? NEGV : pl;           // shifted value (NEG at x=0)
      byte |= ((plm > prev[j]) ? 1u : 0u) << j;   // backtrack decision bit (unused at x=0)
      bool valid = (x < xlen) && (y < ylen) && (x <= y) && (x < TX);
      float lp = valid ? row[x] : NEGV;
      cur[j] = lp + fmaxf(prev[j], plm);
    }
    bb[(size_t)y * 64 + lane] = (unsigned char)byte;
    #pragma unroll
    for (int j = 0; j < 7; ++j) prev[j] = cur[j];
  }
  __threadfence();
  __syncthreads();
  if (lane == 0) {
    int x = xlen - 1;
    float cnt = 0.f;
    float* hb = hard + (size_t)b * TX * TY;
    for (int y = TY - 1; y >= 0; --y) {
      if (y < ylen) {
        hb[(size_t)x * TY + y] = 1.0f;
        cnt += 1.f;
        if (y > 0 && x > 0) {
          bool dec = (x == y) || (((bb[(size_t)y * 64 + x / 7] >> (x % 7)) & 1) != 0);
          if (dec) { dur[b * TX + x] = cnt; cnt = 0.f; x -= 1; }
        }
      }
    }
    dur[b * TX + x] = cnt;
  }
}

extern "C" void kernel_launch(void* const* d_in, const int* in_sizes, int n_in,
                              void* d_out, int out_size, void* d_ws, size_t ws_size,
                              hipStream_t stream) {
  const float* mel_x  = (const float*)d_in[0];
  const float* txt_x  = (const float*)d_in[1];
  const float* mel_w1 = (const float*)d_in[2];
  const float* mel_b1 = (const float*)d_in[3];
  const float* mel_w2 = (const float*)d_in[4];
  const float* mel_b2 = (const float*)d_in[5];
  const float* txt_w1 = (const float*)d_in[6];
  const float* txt_b1 = (const float*)d_in[7];
  const float* txt_w2 = (const float*)d_in[8];
  const float* txt_b2 = (const float*)d_in[9];
  const float* wq     = (const float*)d_in[10];
  const float* bq     = (const float*)d_in[11];
  const float* wk     = (const float*)d_in[12];
  const float* bk     = (const float*)d_in[13];
  const int*   xl     = (const int*)d_in[14];
  const int*   yl     = (const int*)d_in[15];

  float* ws = (float*)d_ws;
  // repacked weights
  const size_t WM1R = 0;                       //  400*1536
  const size_t WM2R = 614400;                  // 3840*384
  const size_t WT1R = 2088960;                 // 1536*1536
  const size_t WT2R = 4448256;                 // 2304*384
  const size_t WQT  = 5332992;                 //  384*384
  const size_t WKT  = 5480448;                 //  384*384
  // activations (with lifetime aliasing)
  const size_t HMEL = 5627904;                 // 16*1600*768
  const size_t HTXT = 25288704;                // 16*400*768
  const size_t MELP = 30203904;                // 16*1600*384
  const size_t TXTP = 40034304;                // 16*400*384   (end: 42,491,904 floats = 170 MB)
  const size_t QB   = HMEL;                    // q aliases dead h_mel
  const size_t KTB  = HTXT;                    // kT aliases dead h_txt
  const size_t BITS = MELP;                    // DP bits alias dead mel_proj

  float* out = (float*)d_out;
  float* o_attn = out;
  float* o_logp = out + (size_t)10240000;
  float* o_hard = out + (size_t)20480000;
  float* o_dur  = out + (size_t)30720000;

  hipMemsetAsync(o_hard, 0, (size_t)(10240000 + 6400) * sizeof(float), stream);

  auto tp = [&](const float* in, float* o, int C, int R) {
    int n = C * R;
    transpose_k<<<(n + 255) / 256, 256, 0, stream>>>(in, o, C, R);
  };
  tp(mel_w1, ws + WM1R, 1536, 400);
  tp(mel_w2, ws + WM2R, 384, 3840);
  tp(txt_w1, ws + WT1R, 1536, 1536);
  tp(txt_w2, ws + WT2R, 384, 2304);
  tp(wq,     ws + WQT,  384, 384);
  tp(wk,     ws + WKT,  384, 384);

  conv_glu_k<512, 3, 400><<<dim3(25, B), 256, 0, stream>>>(txt_x, ws + WT1R, txt_b1, xl, ws + HTXT);
  conv_glu_k<80, 5, 1600><<<dim3(100, B), 256, 0, stream>>>(mel_x, ws + WM1R, mel_b1, yl, ws + HMEL);
  conv2_k<768, 3, 400,  true,  false><<<dim3(9, B),  192, 0, stream>>>(ws + HTXT, ws + WT2R, txt_b2, xl, ws + TXTP);
  conv2_k<768, 5, 1600, true,  false><<<dim3(34, B), 192, 0, stream>>>(ws + HMEL, ws + WM2R, mel_b2, yl, ws + MELP);
  conv2_k<384, 1, 1600, false, false><<<dim3(34, B), 192, 0, stream>>>(ws + MELP, ws + WQT, bq, yl, ws + QB);
  conv2_k<384, 1, 400,  false, true ><<<dim3(9, B),  192, 0, stream>>>(ws + TXTP, ws + WKT, bk, xl, ws + KTB);
  scores_k<<<dim3(100, B), 512, 0, stream>>>(ws + QB, ws + KTB, xl, yl, o_attn, o_logp);
  mas_k<<<B, 64, 0, stream>>>(o_logp, xl, yl, (unsigned char*)(ws + BITS), o_hard, o_dur);
}

// Round 2
// 2872.811 us; speedup vs baseline: 1.8621x; 1.8621x over previous
//
#include <hip/hip_runtime.h>
#include <cstdint>

#define B 16
#define TY 1600
#define TX 400
#define MAS 384
#define HID 768
#define NEGV -1e9f

typedef __bf16 bf16x8 __attribute__((ext_vector_type(8)));
typedef float  f32x4  __attribute__((ext_vector_type(4)));

__device__ __forceinline__ f32x4 mfma16(bf16x8 a, bf16x8 b, f32x4 c) {
  return __builtin_amdgcn_mfma_f32_16x16x32_bf16(a, b, c, 0, 0, 0);
}

// ---------------- generic transpose: out[r*C + c] = in[c*R + r] ----------------
__global__ void transpose_k(const float* __restrict__ in, float* __restrict__ out, int C, int R) {
  int idx = blockIdx.x * 256 + threadIdx.x;
  if (idx >= C * R) return;
  int r = idx / C, c = idx - r * C;
  out[idx] = in[(size_t)c * R + r];
}

// ---------------- fp32 -> bf16 hi/lo split with channel padding ----------------
// in: [rows][CIN], out: [rows][CINP]
__global__ void split_pad_k(const float* __restrict__ in, __bf16* __restrict__ oh,
                            __bf16* __restrict__ ol, int CIN, int CINP, long n) {
  long i = (long)blockIdx.x * 256 + threadIdx.x;
  if (i >= n) return;
  long row = i / CINP; int ci = (int)(i - row * CINP);
  float v = (ci < CIN) ? in[row * CIN + ci] : 0.f;
  __bf16 h = (__bf16)v;
  oh[i] = h; ol[i] = (__bf16)(v - (float)h);
}

// ---------------- weight repack+split: w[N][CIN][K] -> oh/ol[N][k*CINP + ci] ----------------
__global__ void wsplit_k(const float* __restrict__ w, __bf16* __restrict__ oh,
                         __bf16* __restrict__ ol, int CIN, int K_, int CINP, long n) {
  long i = (long)blockIdx.x * 256 + threadIdx.x;
  if (i >= n) return;
  long kdspan = (long)K_ * CINP;
  long nn = i / kdspan; int kd = (int)(i - nn * kdspan);
  int k = kd / CINP, ci = kd - k * CINP;
  float v = (ci < CIN) ? w[(nn * CIN + ci) * K_ + k] : 0.f;
  __bf16 h = (__bf16)v;
  oh[i] = h; ol[i] = (__bf16)(v - (float)h);
}

// ---------------- conv1 + ReGLU, split-bf16 MFMA ----------------
// x (hi/lo): [B,T,CINP]; w (hi/lo): [1536][K*CINP]; out h (hi/lo): [B,T,768]
// block: 256 thr (4 waves 2x2), tile BM=128 rows x 64 GLU pairs
template<int CINP, int K, int T>
__global__ __launch_bounds__(256)
void conv1_mfma(const __bf16* __restrict__ xh, const __bf16* __restrict__ xl,
                const __bf16* __restrict__ wh, const __bf16* __restrict__ wl,
                const float* __restrict__ bias, const int* __restrict__ lens,
                __bf16* __restrict__ hh, __bf16* __restrict__ hl)
{
  constexpr int BM = 128, PAD = K / 2, ROWS = BM + K - 1, KD = K * CINP;
  __shared__ float4 xs[8 * ROWS];  // [spl*4+cg][row], 8 bf16 per entry
  const int b = blockIdx.z, t0 = blockIdx.x * BM, n0 = blockIdx.y * 64;
  const int tid = threadIdx.x, wid = tid >> 6, lane = tid & 63;
  const int wm = wid >> 1, wn = wid & 1, lr = lane & 15, lg = lane >> 4;
  const int len = lens[b];
  const f32x4 Z4 = {0.f, 0.f, 0.f, 0.f};
  f32x4 acc_a[4][2], acc_g[4][2];
  #pragma unroll
  for (int m = 0; m < 4; ++m)
    #pragma unroll
    for (int n = 0; n < 2; ++n) { acc_a[m][n] = Z4; acc_g[m][n] = Z4; }

  #pragma unroll 1
  for (int ci0 = 0; ci0 < CINP; ci0 += 32) {
    __syncthreads();
    for (int e = tid; e < ROWS * 8; e += 256) {
      int row = e >> 3, sc = e & 7, spl = sc >> 2, cg = sc & 3;
      int t = t0 + row - PAD;
      float4 v = {0.f, 0.f, 0.f, 0.f};
      if (t >= 0 && t < len)
        v = *(const float4*)((spl ? xl : xh) + ((size_t)b * T + t) * CINP + ci0 + cg * 8);
      xs[(spl * 4 + cg) * ROWS + row] = v;
    }
    __syncthreads();
    #pragma unroll
    for (int k = 0; k < K; ++k) {
      bf16x8 ah[4], al[4];
      #pragma unroll
      for (int mf = 0; mf < 4; ++mf) {
        int row = wm * 64 + mf * 16 + lr + k;
        ah[mf] = *(const bf16x8*)&xs[lg * ROWS + row];
        al[mf] = *(const bf16x8*)&xs[(4 + lg) * ROWS + row];
      }
      size_t kd = (size_t)k * CINP + ci0 + lg * 8;
      #pragma unroll
      for (int nf = 0; nf < 2; ++nf) {
        int na = n0 + wn * 32 + nf * 16 + lr;
        bf16x8 bah = *(const bf16x8*)(wh + (size_t)na * KD + kd);
        bf16x8 bal = *(const bf16x8*)(wl + (size_t)na * KD + kd);
        bf16x8 bgh = *(const bf16x8*)(wh + (size_t)(na + HID) * KD + kd);
        bf16x8 bgl = *(const bf16x8*)(wl + (size_t)(na + HID) * KD + kd);
        #pragma unroll
        for (int mf = 0; mf < 4; ++mf) {
          acc_a[mf][nf] = mfma16(ah[mf], bah, acc_a[mf][nf]);
          acc_a[mf][nf] = mfma16(ah[mf], bal, acc_a[mf][nf]);
          acc_a[mf][nf] = mfma16(al[mf], bah, acc_a[mf][nf]);
          acc_g[mf][nf] = mfma16(ah[mf], bgh, acc_g[mf][nf]);
          acc_g[mf][nf] = mfma16(ah[mf], bgl, acc_g[mf][nf]);
          acc_g[mf][nf] = mfma16(al[mf], bgh, acc_g[mf][nf]);
        }
      }
    }
  }
  #pragma unroll
  for (int nf = 0; nf < 2; ++nf) {
    int c = n0 + wn * 32 + nf * 16 + lr;
    float ba = bias[c], bg = bias[c + HID];
    #pragma unroll
    for (int mf = 0; mf < 4; ++mf) {
      #pragma unroll
      for (int r = 0; r < 4; ++r) {
        int t = t0 + wm * 64 + mf * 16 + lg * 4 + r;
        if (t < T) {
          float a = acc_a[mf][nf][r] + ba;
          float g = acc_g[mf][nf][r] + bg;
          float v = a * fmaxf(g, 0.f);
          __bf16 vh = (__bf16)v;
          size_t o = ((size_t)b * T + t) * HID + c;
          hh[o] = vh;
          hl[o] = (__bf16)(v - (float)vh);
        }
      }
    }
  }
}

// ---------------- conv2, split-bf16 MFMA -> fp32 out (masked, +bias) ----------------
// x (hi/lo): [B,T,CINP]; w (hi/lo): [384][K*CINP]; out: [B,T,384]
// block: 256 thr (4 waves 2x2), tile BM=128 rows x BN=128 cols
template<int CINP, int K, int T>
__global__ __launch_bounds__(256)
void conv2_mfma(const __bf16* __restrict__ xh, const __bf16* __restrict__ xl,
                const __bf16* __restrict__ wh, const __bf16* __restrict__ wl,
                const float* __restrict__ bias, const int* __restrict__ lens,
                float* __restrict__ out)
{
  constexpr int BM = 128, PAD = K / 2, ROWS = BM + K - 1, KD = K * CINP;
  __shared__ float4 xs[8 * ROWS];
  const int b = blockIdx.z, t0 = blockIdx.x * BM, n0 = blockIdx.y * 128;
  const int tid = threadIdx.x, wid = tid >> 6, lane = tid & 63;
  const int wm = wid >> 1, wn = wid & 1, lr = lane & 15, lg = lane >> 4;
  const int len = lens[b];
  const f32x4 Z4 = {0.f, 0.f, 0.f, 0.f};
  f32x4 acc[4][4];
  #pragma unroll
  for (int m = 0; m < 4; ++m)
    #pragma unroll
    for (int n = 0; n < 4; ++n) acc[m][n] = Z4;

  #pragma unroll 1
  for (int ci0 = 0; ci0 < CINP; ci0 += 32) {
    __syncthreads();
    for (int e = tid; e < ROWS * 8; e += 256) {
      int row = e >> 3, sc = e & 7, spl = sc >> 2, cg = sc & 3;
      int t = t0 + row - PAD;
      float4 v = {0.f, 0.f, 0.f, 0.f};
      if (t >= 0 && t < len)
        v = *(const float4*)((spl ? xl : xh) + ((size_t)b * T + t) * CINP + ci0 + cg * 8);
      xs[(spl * 4 + cg) * ROWS + row] = v;
    }
    __syncthreads();
    #pragma unroll
    for (int k = 0; k < K; ++k) {
      bf16x8 ah[4], al[4];
      #pragma unroll
      for (int mf = 0; mf < 4; ++mf) {
        int row = wm * 64 + mf * 16 + lr + k;
        ah[mf] = *(const bf16x8*)&xs[lg * ROWS + row];
        al[mf] = *(const bf16x8*)&xs[(4 + lg) * ROWS + row];
      }
      size_t kd = (size_t)k * CINP + ci0 + lg * 8;
      #pragma unroll
      for (int nf = 0; nf < 4; ++nf) {
        int nc = n0 + wn * 64 + nf * 16 + lr;
        bf16x8 bh = *(const bf16x8*)(wh + (size_t)nc * KD + kd);
        bf16x8 bl = *(const bf16x8*)(wl + (size_t)nc * KD + kd);
        #pragma unroll
        for (int mf = 0; mf < 4; ++mf) {
          acc[mf][nf] = mfma16(ah[mf], bh, acc[mf][nf]);
          acc[mf][nf] = mfma16(ah[mf], bl, acc[mf][nf]);
          acc[mf][nf] = mfma16(al[mf], bh, acc[mf][nf]);
        }
      }
    }
  }
  #pragma unroll
  for (int nf = 0; nf < 4; ++nf) {
    int c = n0 + wn * 64 + nf * 16 + lr;
    float bb = bias[c];
    #pragma unroll
    for (int mf = 0; mf < 4; ++mf) {
      #pragma unroll
      for (int r = 0; r < 4; ++r) {
        int t = t0 + wm * 64 + mf * 16 + lg * 4 + r;
        if (t < T)
          out[((size_t)b * T + t) * MAS + c] = (t < len) ? acc[mf][nf][r] + bb : 0.f;
      }
    }
  }
}

// ---------------- conv2 / linear fp32 (kept for q/k projections) ----------------
template<int CIN, int K, int T, bool MASK, bool STORET>
__global__ __launch_bounds__(192)
void conv2_k(const float* __restrict__ x, const float* __restrict__ wr,
             const float* __restrict__ bias, const int* __restrict__ lens,
             float* __restrict__ out)
{
  constexpr int TT = 48, CICH = 96, PAD = K / 2, ROWS = TT + K - 1;
  __shared__ float xs[ROWS * CICH];
  const int b = blockIdx.y, t0 = blockIdx.x * TT, tid = threadIdx.x;
  const int len = lens[b];
  const int c0 = tid, c1 = tid + 192;
  float acc0[TT] = {}, acc1[TT] = {};
  for (int ci0 = 0; ci0 < CIN; ci0 += CICH) {
    __syncthreads();
    for (int e = tid; e < ROWS * CICH; e += 192) {
      int row = e / CICH, ci = e - row * CICH;
      int t = t0 + row - PAD;
      xs[e] = (t >= 0 && t < len) ? x[((size_t)b * T + t) * CIN + ci0 + ci] : 0.f;
    }
    __syncthreads();
    for (int ci = 0; ci < CICH; ++ci) {
      #pragma unroll
      for (int k = 0; k < K; ++k) {
        const float* wrow = wr + (size_t)((ci0 + ci) * K + k) * MAS;
        float w0 = wrow[c0], w1 = wrow[c1];
        #pragma unroll
        for (int t = 0; t < TT; ++t) {
          float xv = xs[(t + k) * CICH + ci];
          acc0[t] = fmaf(xv, w0, acc0[t]);
          acc1[t] = fmaf(xv, w1, acc1[t]);
        }
      }
    }
  }
  const float b0 = bias[c0], b1 = bias[c1];
  #pragma unroll
  for (int t = 0; t < TT; ++t) {
    int tt = t0 + t;
    if (tt < T) {
      float v0 = acc0[t] + b0, v1 = acc1[t] + b1;
      if (MASK && tt >= len) { v0 = 0.f; v1 = 0.f; }
      if (STORET) {
        out[((size_t)b * MAS + c0) * T + tt] = v0;
        out[((size_t)b * MAS + c1) * T + tt] = v1;
      } else {
        size_t o = ((size_t)b * T + tt) * MAS;
        out[o + c0] = v0; out[o + c1] = v1;
      }
    }
  }
}

// ---------------- scores + softmax + safe_log ----------------
__global__ __launch_bounds__(512)
void scores_k(const float* __restrict__ q, const float* __restrict__ kT,
              const int* __restrict__ xl, const int* __restrict__ yl,
              float* __restrict__ oattn, float* __restrict__ ologp)
{
  __shared__ float qs[16 * 384];
  __shared__ float tmp[8];
  const int b = blockIdx.y, y0 = blockIdx.x * 16, tid = threadIdx.x;
  for (int e = tid; e < 16 * 384; e += 512)
    qs[e] = q[((size_t)b * TY + (y0 + e / 384)) * 384 + (e - (e / 384) * 384)];
  __syncthreads();
  float acc[16];
  #pragma unroll
  for (int i = 0; i < 16; ++i) acc[i] = 0.f;
  const int x = tid;
  if (x < TX) {
    const float* kb = kT + (size_t)b * MAS * TX + x;
    for (int d = 0; d < 384; d += 4) {
      float k0 = kb[(size_t)(d + 0) * TX], k1 = kb[(size_t)(d + 1) * TX];
      float k2 = kb[(size_t)(d + 2) * TX], k3 = kb[(size_t)(d + 3) * TX];
      #pragma unroll
      for (int yy = 0; yy < 16; ++yy) {
        float4 qv = *(const float4*)&qs[yy * 384 + d];
        acc[yy] = fmaf(qv.x, k0, fmaf(qv.y, k1, fmaf(qv.z, k2, fmaf(qv.w, k3, acc[yy]))));
      }
    }
  }
  const int xlen = xl[b], ylen = yl[b];
  const float scale = 0.05103103630798288f;  // 1/sqrt(384)
  const bool xpad = (x >= xlen);
  const int wv = tid >> 6, ln = tid & 63;
  #pragma unroll 1
  for (int yy = 0; yy < 16; ++yy) {
    int y = y0 + yy;
    float s = -3.0e38f;
    if (x < TX) {
      s = acc[yy] * scale;
      if (xpad && (y >= ylen)) s = -1e-9f;
    }
    float m = s;
    for (int off = 32; off; off >>= 1) m = fmaxf(m, __shfl_xor(m, off));
    if (ln == 0) tmp[wv] = m;
    __syncthreads();
    float mx = fmaxf(fmaxf(fmaxf(tmp[0], tmp[1]), fmaxf(tmp[2], tmp[3])),
                     fmaxf(fmaxf(tmp[4], tmp[5]), fmaxf(tmp[6], tmp[7])));
    __syncthreads();
    float e = (x < TX) ? expf(s - mx) : 0.f;
    float sm = e;
    for (int off = 32; off; off >>= 1) sm += __shfl_xor(sm, off);
    if (ln == 0) tmp[wv] = sm;
    __syncthreads();
    float tot = tmp[0] + tmp[1] + tmp[2] + tmp[3] + tmp[4] + tmp[5] + tmp[6] + tmp[7];
    __syncthreads();
    if (x < TX) {
      float w = e / tot;
      size_t o = ((size_t)b * TY + y) * TX + x;
      oattn[o] = w;
      ologp[o] = logf(w + 1e-6f);
    }
  }
}

// ---------------- MAS: forward DP (1 wave/batch) + bit-recorded backtrack ----------------
__global__ __launch_bounds__(64)
void mas_k(const float* __restrict__ logprob, const int* __restrict__ xl, const int* __restrict__ yl,
           unsigned char* __restrict__ bits, float* __restrict__ hard, float* __restrict__ dur)
{
  const int b = blockIdx.x;
  const int lane = threadIdx.x;
  const int xlen = xl[b], ylen = yl[b];
  const int xbase = lane * 7;
  float prev[7];
  #pragma unroll
  for (int j = 0; j < 7; ++j) prev[j] = (xbase + j == 0) ? 0.f : NEGV;
  const float* lpb = logprob + (size_t)b * TY * TX;
  unsigned char* bb = bits + (size_t)b * TY * 64;
  for (int y = 0; y < TY; ++y) {
    float left = __shfl_up(prev[6], 1);
    const float* row = lpb + (size_t)y * TX;
    unsigned byte = 0;
    float cur[7];
    #pragma unroll
    for (int j = 0; j < 7; ++j) {
      int x = xbase + j;
      float pl  = (j == 0) ? left : prev[j - 1];
      float plm = (x == 0) ? NEGV : pl;
      byte |= ((plm > prev[j]) ? 1u : 0u) << j;
      bool valid = (x < xlen) && (y < ylen) && (x <= y) && (x < TX);
      float lp = valid ? row[x] : NEGV;
      cur[j] = lp + fmaxf(prev[j], plm);
    }
    bb[(size_t)y * 64 + lane] = (unsigned char)byte;
    #pragma unroll
    for (int j = 0; j < 7; ++j) prev[j] = cur[j];
  }
  __threadfence();
  __syncthreads();
  if (lane == 0) {
    int x = xlen - 1;
    float cnt = 0.f;
    float* hb = hard + (size_t)b * TX * TY;
    for (int y = TY - 1; y >= 0; --y) {
      if (y < ylen) {
        hb[(size_t)x * TY + y] = 1.0f;
        cnt += 1.f;
        if (y > 0 && x > 0) {
          bool dec = (x == y) || (((bb[(size_t)y * 64 + x / 7] >> (x % 7)) & 1) != 0);
          if (dec) { dur[b * TX + x] = cnt; cnt = 0.f; x -= 1; }
        }
      }
    }
    dur[b * TX + x] = cnt;
  }
}

extern "C" void kernel_launch(void* const* d_in, const int* in_sizes, int n_in,
                              void* d_out, int out_size, void* d_ws, size_t ws_size,
                              hipStream_t stream) {
  const float* mel_x  = (const float*)d_in[0];
  const float* txt_x  = (const float*)d_in[1];
  const float* mel_w1 = (const float*)d_in[2];
  const float* mel_b1 = (const float*)d_in[3];
  const float* mel_w2 = (const float*)d_in[4];
  const float* mel_b2 = (const float*)d_in[5];
  const float* txt_w1 = (const float*)d_in[6];
  const float* txt_b1 = (const float*)d_in[7];
  const float* txt_w2 = (const float*)d_in[8];
  const float* txt_b2 = (const float*)d_in[9];
  const float* wq     = (const float*)d_in[10];
  const float* bq     = (const float*)d_in[11];
  const float* wk     = (const float*)d_in[12];
  const float* bk     = (const float*)d_in[13];
  const int*   xl     = (const int*)d_in[14];
  const int*   yl     = (const int*)d_in[15];

  char* wsb = (char*)d_ws;
  // byte offsets (all sizes multiples of 256)
  constexpr size_t MXH  = 0;                      // 16*1600*96*2   = 4,915,200
  constexpr size_t MXL  = MXH  + 4915200;
  constexpr size_t TXH  = MXL  + 4915200;         // 16*400*512*2   = 6,553,600
  constexpr size_t TXL  = TXH  + 6553600;
  constexpr size_t W1MH = TXL  + 6553600;         // 1536*480*2     = 1,474,560
  constexpr size_t W1ML = W1MH + 1474560;
  constexpr size_t W2MH = W1ML + 1474560;         // 384*3840*2     = 2,949,120
  constexpr size_t W2ML = W2MH + 2949120;
  constexpr size_t W1TH = W2ML + 2949120;         // 1536*1536*2    = 4,718,592
  constexpr size_t W1TL = W1TH + 4718592;
  constexpr size_t W2TH = W1TL + 4718592;         // 384*2304*2     = 1,769,472
  constexpr size_t W2TL = W2TH + 1769472;
  constexpr size_t WQT  = W2TL + 1769472;         // 384*384*4      = 589,824
  constexpr size_t WKT  = WQT  + 589824;
  constexpr size_t HH0  = WKT  + 589824;          // 16*1600*768*2  = 39,321,600 (hm_h / ht_h / q lo-half)
  constexpr size_t HH1  = HH0  + 39321600;        // hm_l / ht_l / q hi-half
  constexpr size_t PROJ = HH1  + 39321600;        // 16*1600*384*4  = 40,960,000 (txt_proj then mel_proj)
  constexpr size_t KT   = PROJ + 40960000;        // 16*400*384*4   = 10,240,000
  constexpr size_t BITS = KT   + 10240000;        // 16*1600*64     = 1,638,400

  float* out = (float*)d_out;
  float* o_attn = out;
  float* o_logp = out + (size_t)10240000;
  float* o_hard = out + (size_t)20480000;
  float* o_dur  = out + (size_t)30720000;

  hipMemsetAsync(o_hard, 0, (size_t)(10240000 + 6400) * sizeof(float), stream);

  // input splits (channel-padded)
  split_pad_k<<<9600, 256, 0, stream>>>(mel_x, (__bf16*)(wsb + MXH), (__bf16*)(wsb + MXL), 80, 96, 2457600L);
  split_pad_k<<<12800, 256, 0, stream>>>(txt_x, (__bf16*)(wsb + TXH), (__bf16*)(wsb + TXL), 512, 512, 3276800L);
  // weight repack+split
  wsplit_k<<<2880, 256, 0, stream>>>(mel_w1, (__bf16*)(wsb + W1MH), (__bf16*)(wsb + W1ML), 80, 5, 96, 737280L);
  wsplit_k<<<5760, 256, 0, stream>>>(mel_w2, (__bf16*)(wsb + W2MH), (__bf16*)(wsb + W2ML), 768, 5, 768, 1474560L);
  wsplit_k<<<9216, 256, 0, stream>>>(txt_w1, (__bf16*)(wsb + W1TH), (__bf16*)(wsb + W1TL), 512, 3, 512, 2359296L);
  wsplit_k<<<3456, 256, 0, stream>>>(txt_w2, (__bf16*)(wsb + W2TH), (__bf16*)(wsb + W2TL), 768, 3, 768, 884736L);
  // q/k weights (fp32 path)
  transpose_k<<<576, 256, 0, stream>>>(wq, (float*)(wsb + WQT), 384, 384);
  transpose_k<<<576, 256, 0, stream>>>(wk, (float*)(wsb + WKT), 384, 384);

  // text pipeline
  conv1_mfma<512, 3, 400><<<dim3(4, 12, B), 256, 0, stream>>>(
      (const __bf16*)(wsb + TXH), (const __bf16*)(wsb + TXL),
      (const __bf16*)(wsb + W1TH), (const __bf16*)(wsb + W1TL),
      txt_b1, xl, (__bf16*)(wsb + HH0), (__bf16*)(wsb + HH1));
  conv2_mfma<768, 3, 400><<<dim3(4, 3, B), 256, 0, stream>>>(
      (const __bf16*)(wsb + HH0), (const __bf16*)(wsb + HH1),
      (const __bf16*)(wsb + W2TH), (const __bf16*)(wsb + W2TL),
      txt_b2, xl, (float*)(wsb + PROJ));
  conv2_k<384, 1, 400, false, true><<<dim3(9, B), 192, 0, stream>>>(
      (const float*)(wsb + PROJ), (const float*)(wsb + WKT), bk, xl, (float*)(wsb + KT));

  // mel pipeline
  conv1_mfma<96, 5, 1600><<<dim3(13, 12, B), 256, 0, stream>>>(
      (const __bf16*)(wsb + MXH), (const __bf16*)(wsb + MXL),
      (const __bf16*)(wsb + W1MH), (const __bf16*)(wsb + W1ML),
      mel_b1, yl, (__bf16*)(wsb + HH0), (__bf16*)(wsb + HH1));
  conv2_mfma<768, 5, 1600><<<dim3(13, 3, B), 256, 0, stream>>>(
      (const __bf16*)(wsb + HH0), (const __bf16*)(wsb + HH1),
      (const __bf16*)(wsb + W2MH), (const __bf16*)(wsb + W2ML),
      mel_b2, yl, (float*)(wsb + PROJ));
  conv2_k<384, 1, 1600, false, false><<<dim3(34, B), 192, 0, stream>>>(
      (const float*)(wsb + PROJ), (const float*)(wsb + WQT), bq, yl, (float*)(wsb + HH0));

  // attention + MAS
  scores_k<<<dim3(100, B), 512, 0, stream>>>(
      (const float*)(wsb + HH0), (const float*)(wsb + KT), xl, yl, o_attn, o_logp);
  mas_k<<<B, 64, 0, stream>>>(o_logp, xl, yl, (unsigned char*)(wsb + BITS), o_hard, o_dur);
}

// Round 3
// 1876.772 us; speedup vs baseline: 2.8503x; 1.5307x over previous
//
#include <hip/hip_runtime.h>
#include <cstdint>

#define B 16
#define TY 1600
#define TX 400
#define MAS 384
#define HID 768
#define NEGV -1e9f

typedef __bf16 bf16x8 __attribute__((ext_vector_type(8)));
typedef float  f32x4  __attribute__((ext_vector_type(4)));

__device__ __forceinline__ f32x4 mfma16(bf16x8 a, bf16x8 b, f32x4 c) {
  return __builtin_amdgcn_mfma_f32_16x16x32_bf16(a, b, c, 0, 0, 0);
}

// ---------------- fp32 -> bf16 hi/lo split with channel padding ----------------
__global__ void split_pad_k(const float* __restrict__ in, __bf16* __restrict__ oh,
                            __bf16* __restrict__ ol, int CIN, int CINP, long n) {
  long i = (long)blockIdx.x * 256 + threadIdx.x;
  if (i >= n) return;
  long row = i / CINP; int ci = (int)(i - row * CINP);
  float v = (ci < CIN) ? in[row * CIN + ci] : 0.f;
  __bf16 h = (__bf16)v;
  oh[i] = h; ol[i] = (__bf16)(v - (float)h);
}

// ---------------- weight repack+split: w[N][CIN][K] -> oh/ol[N][k*CINP + ci] ----------------
__global__ void wsplit_k(const float* __restrict__ w, __bf16* __restrict__ oh,
                         __bf16* __restrict__ ol, int CIN, int K_, int CINP, long n) {
  long i = (long)blockIdx.x * 256 + threadIdx.x;
  if (i >= n) return;
  long kdspan = (long)K_ * CINP;
  long nn = i / kdspan; int kd = (int)(i - nn * kdspan);
  int k = kd / CINP, ci = kd - k * CINP;
  float v = (ci < CIN) ? w[(nn * CIN + ci) * K_ + k] : 0.f;
  __bf16 h = (__bf16)v;
  oh[i] = h; ol[i] = (__bf16)(v - (float)h);
}

// ---------------- conv1 + ReGLU, split-bf16 MFMA ----------------
template<int CINP, int K, int T>
__global__ __launch_bounds__(256)
void conv1_mfma(const __bf16* __restrict__ xh, const __bf16* __restrict__ xl,
                const __bf16* __restrict__ wh, const __bf16* __restrict__ wl,
                const float* __restrict__ bias, const int* __restrict__ lens,
                __bf16* __restrict__ hh, __bf16* __restrict__ hl)
{
  constexpr int BM = 128, PAD = K / 2, ROWS = BM + K - 1, KD = K * CINP;
  __shared__ float4 xs[8 * ROWS];
  const int b = blockIdx.z, t0 = blockIdx.x * BM, n0 = blockIdx.y * 64;
  const int tid = threadIdx.x, wid = tid >> 6, lane = tid & 63;
  const int wm = wid >> 1, wn = wid & 1, lr = lane & 15, lg = lane >> 4;
  const int len = lens[b];
  const f32x4 Z4 = {0.f, 0.f, 0.f, 0.f};
  f32x4 acc_a[4][2], acc_g[4][2];
  #pragma unroll
  for (int m = 0; m < 4; ++m)
    #pragma unroll
    for (int n = 0; n < 2; ++n) { acc_a[m][n] = Z4; acc_g[m][n] = Z4; }

  #pragma unroll 1
  for (int ci0 = 0; ci0 < CINP; ci0 += 32) {
    __syncthreads();
    for (int e = tid; e < ROWS * 8; e += 256) {
      int row = e >> 3, sc = e & 7, spl = sc >> 2, cg = sc & 3;
      int t = t0 + row - PAD;
      float4 v = {0.f, 0.f, 0.f, 0.f};
      if (t >= 0 && t < len)
        v = *(const float4*)((spl ? xl : xh) + ((size_t)b * T + t) * CINP + ci0 + cg * 8);
      xs[(spl * 4 + cg) * ROWS + row] = v;
    }
    __syncthreads();
    #pragma unroll
    for (int k = 0; k < K; ++k) {
      bf16x8 ah[4], al[4];
      #pragma unroll
      for (int mf = 0; mf < 4; ++mf) {
        int row = wm * 64 + mf * 16 + lr + k;
        ah[mf] = *(const bf16x8*)&xs[lg * ROWS + row];
        al[mf] = *(const bf16x8*)&xs[(4 + lg) * ROWS + row];
      }
      size_t kd = (size_t)k * CINP + ci0 + lg * 8;
      #pragma unroll
      for (int nf = 0; nf < 2; ++nf) {
        int na = n0 + wn * 32 + nf * 16 + lr;
        bf16x8 bah = *(const bf16x8*)(wh + (size_t)na * KD + kd);
        bf16x8 bal = *(const bf16x8*)(wl + (size_t)na * KD + kd);
        bf16x8 bgh = *(const bf16x8*)(wh + (size_t)(na + HID) * KD + kd);
        bf16x8 bgl = *(const bf16x8*)(wl + (size_t)(na + HID) * KD + kd);
        #pragma unroll
        for (int mf = 0; mf < 4; ++mf) {
          acc_a[mf][nf] = mfma16(ah[mf], bah, acc_a[mf][nf]);
          acc_a[mf][nf] = mfma16(ah[mf], bal, acc_a[mf][nf]);
          acc_a[mf][nf] = mfma16(al[mf], bah, acc_a[mf][nf]);
          acc_g[mf][nf] = mfma16(ah[mf], bgh, acc_g[mf][nf]);
          acc_g[mf][nf] = mfma16(ah[mf], bgl, acc_g[mf][nf]);
          acc_g[mf][nf] = mfma16(al[mf], bgh, acc_g[mf][nf]);
        }
      }
    }
  }
  #pragma unroll
  for (int nf = 0; nf < 2; ++nf) {
    int c = n0 + wn * 32 + nf * 16 + lr;
    float ba = bias[c], bg = bias[c + HID];
    #pragma unroll
    for (int mf = 0; mf < 4; ++mf) {
      #pragma unroll
      for (int r = 0; r < 4; ++r) {
        int t = t0 + wm * 64 + mf * 16 + lg * 4 + r;
        if (t < T) {
          float a = acc_a[mf][nf][r] + ba;
          float g = acc_g[mf][nf][r] + bg;
          float v = a * fmaxf(g, 0.f);
          __bf16 vh = (__bf16)v;
          size_t o = ((size_t)b * T + t) * HID + c;
          hh[o] = vh;
          hl[o] = (__bf16)(v - (float)vh);
        }
      }
    }
  }
}

// ---------------- conv2 / linear, split-bf16 MFMA ----------------
// SPLITOUT: write bf16 hi/lo (masked); else fp32 (+optional transposed store)
template<int CINP, int K, int T, bool MASK, bool SPLITOUT, bool STORET>
__global__ __launch_bounds__(256)
void conv2_mfma(const __bf16* __restrict__ xh, const __bf16* __restrict__ xl,
                const __bf16* __restrict__ wh, const __bf16* __restrict__ wl,
                const float* __restrict__ bias, const int* __restrict__ lens,
                float* __restrict__ out, __bf16* __restrict__ oh, __bf16* __restrict__ ol)
{
  constexpr int BM = 128, PAD = K / 2, ROWS = BM + K - 1, KD = K * CINP;
  __shared__ float4 xs[8 * ROWS];
  const int b = blockIdx.z, t0 = blockIdx.x * BM, n0 = blockIdx.y * 128;
  const int tid = threadIdx.x, wid = tid >> 6, lane = tid & 63;
  const int wm = wid >> 1, wn = wid & 1, lr = lane & 15, lg = lane >> 4;
  const int len = lens[b];
  const f32x4 Z4 = {0.f, 0.f, 0.f, 0.f};
  f32x4 acc[4][4];
  #pragma unroll
  for (int m = 0; m < 4; ++m)
    #pragma unroll
    for (int n = 0; n < 4; ++n) acc[m][n] = Z4;

  #pragma unroll 1
  for (int ci0 = 0; ci0 < CINP; ci0 += 32) {
    __syncthreads();
    for (int e = tid; e < ROWS * 8; e += 256) {
      int row = e >> 3, sc = e & 7, spl = sc >> 2, cg = sc & 3;
      int t = t0 + row - PAD;
      float4 v = {0.f, 0.f, 0.f, 0.f};
      if (t >= 0 && t < len)
        v = *(const float4*)((spl ? xl : xh) + ((size_t)b * T + t) * CINP + ci0 + cg * 8);
      xs[(spl * 4 + cg) * ROWS + row] = v;
    }
    __syncthreads();
    #pragma unroll
    for (int k = 0; k < K; ++k) {
      bf16x8 ah[4], al[4];
      #pragma unroll
      for (int mf = 0; mf < 4; ++mf) {
        int row = wm * 64 + mf * 16 + lr + k;
        ah[mf] = *(const bf16x8*)&xs[lg * ROWS + row];
        al[mf] = *(const bf16x8*)&xs[(4 + lg) * ROWS + row];
      }
      size_t kd = (size_t)k * CINP + ci0 + lg * 8;
      #pragma unroll
      for (int nf = 0; nf < 4; ++nf) {
        int nc = n0 + wn * 64 + nf * 16 + lr;
        bf16x8 bh = *(const bf16x8*)(wh + (size_t)nc * KD + kd);
        bf16x8 bl = *(const bf16x8*)(wl + (size_t)nc * KD + kd);
        #pragma unroll
        for (int mf = 0; mf < 4; ++mf) {
          acc[mf][nf] = mfma16(ah[mf], bh, acc[mf][nf]);
          acc[mf][nf] = mfma16(ah[mf], bl, acc[mf][nf]);
          acc[mf][nf] = mfma16(al[mf], bh, acc[mf][nf]);
        }
      }
    }
  }
  #pragma unroll
  for (int nf = 0; nf < 4; ++nf) {
    int c = n0 + wn * 64 + nf * 16 + lr;
    float bb = bias[c];
    #pragma unroll
    for (int mf = 0; mf < 4; ++mf) {
      #pragma unroll
      for (int r = 0; r < 4; ++r) {
        int t = t0 + wm * 64 + mf * 16 + lg * 4 + r;
        if (t < T) {
          float v = acc[mf][nf][r] + bb;
          if (MASK && t >= len) v = 0.f;
          if (SPLITOUT) {
            __bf16 vh = (__bf16)v;
            size_t o = ((size_t)b * T + t) * MAS + c;
            oh[o] = vh;
            ol[o] = (__bf16)(v - (float)vh);
          } else if (STORET) {
            out[((size_t)b * MAS + c) * T + t] = v;
          } else {
            out[((size_t)b * T + t) * MAS + c] = v;
          }
        }
      }
    }
  }
}

// ---------------- scores + softmax + safe_log ----------------
__global__ __launch_bounds__(512)
void scores_k(const float* __restrict__ q, const float* __restrict__ kT,
              const int* __restrict__ xl, const int* __restrict__ yl,
              float* __restrict__ oattn, float* __restrict__ ologp)
{
  __shared__ float qs[16 * 384];
  __shared__ float tmp[8];
  const int b = blockIdx.y, y0 = blockIdx.x * 16, tid = threadIdx.x;
  for (int e = tid; e < 16 * 384; e += 512)
    qs[e] = q[((size_t)b * TY + (y0 + e / 384)) * 384 + (e - (e / 384) * 384)];
  __syncthreads();
  float acc[16];
  #pragma unroll
  for (int i = 0; i < 16; ++i) acc[i] = 0.f;
  const int x = tid;
  if (x < TX) {
    const float* kb = kT + (size_t)b * MAS * TX + x;
    for (int d = 0; d < 384; d += 4) {
      float k0 = kb[(size_t)(d + 0) * TX], k1 = kb[(size_t)(d + 1) * TX];
      float k2 = kb[(size_t)(d + 2) * TX], k3 = kb[(size_t)(d + 3) * TX];
      #pragma unroll
      for (int yy = 0; yy < 16; ++yy) {
        float4 qv = *(const float4*)&qs[yy * 384 + d];
        acc[yy] = fmaf(qv.x, k0, fmaf(qv.y, k1, fmaf(qv.z, k2, fmaf(qv.w, k3, acc[yy]))));
      }
    }
  }
  const int xlen = xl[b], ylen = yl[b];
  const float scale = 0.05103103630798288f;
  const bool xpad = (x >= xlen);
  const int wv = tid >> 6, ln = tid & 63;
  #pragma unroll 1
  for (int yy = 0; yy < 16; ++yy) {
    int y = y0 + yy;
    float s = -3.0e38f;
    if (x < TX) {
      s = acc[yy] * scale;
      if (xpad && (y >= ylen)) s = -1e-9f;
    }
    float m = s;
    for (int off = 32; off; off >>= 1) m = fmaxf(m, __shfl_xor(m, off));
    if (ln == 0) tmp[wv] = m;
    __syncthreads();
    float mx = fmaxf(fmaxf(fmaxf(tmp[0], tmp[1]), fmaxf(tmp[2], tmp[3])),
                     fmaxf(fmaxf(tmp[4], tmp[5]), fmaxf(tmp[6], tmp[7])));
    __syncthreads();
    float e = (x < TX) ? expf(s - mx) : 0.f;
    float sm = e;
    for (int off = 32; off; off >>= 1) sm += __shfl_xor(sm, off);
    if (ln == 0) tmp[wv] = sm;
    __syncthreads();
    float tot = tmp[0] + tmp[1] + tmp[2] + tmp[3] + tmp[4] + tmp[5] + tmp[6] + tmp[7];
    __syncthreads();
    if (x < TX) {
      float w = e / tot;
      size_t o = ((size_t)b * TY + y) * TX + x;
      oattn[o] = w;
      ologp[o] = logf(w + 1e-6f);
    }
  }
}

// ---------------- MAS: prefetched forward DP + chunked wave-parallel backtrack ----------------
// lane l owns x in [8l, 8l+8); bits[b][y][byte=x>>3] bit (x&7) = (v[y-1][x-1] > v[y-1][x])
__global__ __launch_bounds__(64)
void mas_k(const float* __restrict__ logprob, const int* __restrict__ xl, const int* __restrict__ yl,
           unsigned char* __restrict__ bits, float* __restrict__ hard, float* __restrict__ dur)
{
  const int b = blockIdx.x;
  const int lane = threadIdx.x;
  const int xlen = xl[b], ylen = yl[b];
  const int xbase = lane * 8;
  const float* lpb = logprob + (size_t)b * TY * TX;
  unsigned char* bb = bits + (size_t)b * TY * 64;

  float prev[8];
  bool xok[8];
  #pragma unroll
  for (int j = 0; j < 8; ++j) {
    prev[j] = (xbase + j == 0) ? 0.f : NEGV;
    xok[j] = (xbase + j < xlen);
  }

  const bool doload = (xbase < TX);
  constexpr int PF = 8;
  float4 bufa[PF], bufb[PF];
  #pragma unroll
  for (int p = 0; p < PF; ++p) {
    if (doload) {
      const float* r = lpb + (size_t)p * TX + xbase;
      bufa[p] = *(const float4*)r;
      bufb[p] = *(const float4*)(r + 4);
    }
  }

  auto step = [&](int y, float4 v0, float4 v1) {
    float left = __shfl_up(prev[7], 1);
    float v[8] = {v0.x, v0.y, v0.z, v0.w, v1.x, v1.y, v1.z, v1.w};
    unsigned byte = 0;
    float cur[8];
    #pragma unroll
    for (int j = 0; j < 8; ++j) {
      int x = xbase + j;
      float pl = (j == 0) ? left : prev[j - 1];
      float plm = (x == 0) ? NEGV : pl;
      byte |= ((plm > prev[j]) ? 1u : 0u) << j;
      bool valid = xok[j] && (x <= y);
      float lp = valid ? v[j] : NEGV;
      cur[j] = lp + fmaxf(prev[j], plm);
    }
    bb[(size_t)y * 64 + lane] = (unsigned char)byte;
    #pragma unroll
    for (int j = 0; j < 8; ++j) prev[j] = cur[j];
  };

  const int nfull = ylen & ~(PF - 1);
  int y = 0;
  for (; y < nfull; y += PF) {
    #pragma unroll
    for (int u = 0; u < PF; ++u) {
      step(y + u, bufa[u], bufb[u]);
      int yn = y + u + PF;
      if (yn < ylen && doload) {
        const float* r = lpb + (size_t)yn * TX + xbase;
        bufa[u] = *(const float4*)r;
        bufb[u] = *(const float4*)(r + 4);
      }
    }
  }
  #pragma unroll
  for (int u = 0; u < PF; ++u) {
    if (y + u < ylen) step(y + u, bufa[u], bufb[u]);
  }

  __threadfence();
  __syncthreads();

  // chunked backtrack: all lanes maintain identical scalar state; bits pulled via shfl
  int x = xlen - 1;
  float cnt = 0.f;
  float* hb = hard + (size_t)b * TX * TY;
  float* db = dur + (size_t)b * TX;

  for (int y0 = ylen - 1; y0 >= 0; y0 -= 64) {
    int lo = x - 63; if (lo < 0) lo = 0;
    const int wb = (lo >> 3) & ~3;          // aligned byte base; window [wb, wb+12)
    int ry = y0 - lane;
    unsigned w0 = 0, w1 = 0, w2 = 0;
    if (ry >= 0) {
      const unsigned* rp = (const unsigned*)(bb + (size_t)ry * 64 + wb);
      w0 = rp[0]; w1 = rp[1]; w2 = rp[2];
    }
    int yend = y0 - 63; if (yend < 0) yend = 0;
    for (int yy = y0; yy >= yend; --yy) {
      int k = y0 - yy;
      unsigned s0 = __shfl(w0, k), s1 = __shfl(w1, k), s2 = __shfl(w2, k);
      if (lane == 0) hb[(size_t)x * TY + yy] = 1.0f;
      cnt += 1.f;
      if (yy > 0 && x > 0) {
        int boff = (x >> 3) - wb;
        unsigned wsel = boff < 4 ? s0 : (boff < 8 ? s1 : s2);
        unsigned byte = wsel >> ((boff & 3) * 8);
        bool dec = (x == yy) || ((byte >> (x & 7)) & 1);
        if (dec) { if (lane == 0) db[x] = cnt; cnt = 0.f; x -= 1; }
      }
    }
  }
  if (lane == 0) db[x] = cnt;
}

extern "C" void kernel_launch(void* const* d_in, const int* in_sizes, int n_in,
                              void* d_out, int out_size, void* d_ws, size_t ws_size,
                              hipStream_t stream) {
  const float* mel_x  = (const float*)d_in[0];
  const float* txt_x  = (const float*)d_in[1];
  const float* mel_w1 = (const float*)d_in[2];
  const float* mel_b1 = (const float*)d_in[3];
  const float* mel_w2 = (const float*)d_in[4];
  const float* mel_b2 = (const float*)d_in[5];
  const float* txt_w1 = (const float*)d_in[6];
  const float* txt_b1 = (const float*)d_in[7];
  const float* txt_w2 = (const float*)d_in[8];
  const float* txt_b2 = (const float*)d_in[9];
  const float* wq     = (const float*)d_in[10];
  const float* bq     = (const float*)d_in[11];
  const float* wk     = (const float*)d_in[12];
  const float* bk     = (const float*)d_in[13];
  const int*   xl     = (const int*)d_in[14];
  const int*   yl     = (const int*)d_in[15];

  char* wsb = (char*)d_ws;
  // byte offsets
  constexpr size_t MXH  = 0;                        // 16*1600*96*2   = 4,915,200
  constexpr size_t MXL  = MXH  + 4915200;
  constexpr size_t TXH  = MXL  + 4915200;           // 16*400*512*2   = 6,553,600
  constexpr size_t TXL  = TXH  + 6553600;           // ends 22,937,600
  constexpr size_t TPH  = TXH;                      // txt proj hi (4,915,200) aliases dead TXH/TXL
  constexpr size_t TPL  = TXH  + 4915200;
  constexpr size_t W1MH = TXL  + 6553600;           // 1536*5*96*2  = 1,474,560
  constexpr size_t W1ML = W1MH + 1474560;
  constexpr size_t W2MH = W1ML + 1474560;           // 384*5*768*2  = 2,949,120
  constexpr size_t W2ML = W2MH + 2949120;
  constexpr size_t W1TH = W2ML + 2949120;           // 1536*3*512*2 = 4,718,592
  constexpr size_t W1TL = W1TH + 4718592;
  constexpr size_t W2TH = W1TL + 4718592;           // 384*3*768*2  = 1,769,472
  constexpr size_t W2TL = W2TH + 1769472;
  constexpr size_t WQH  = W2TL + 1769472;           // 384*384*2    = 294,912
  constexpr size_t WQL  = WQH  + 294912;
  constexpr size_t WKH  = WQL  + 294912;
  constexpr size_t WKL  = WKH  + 294912;
  constexpr size_t HH   = WKL  + 294912;            // 16*1600*768*2 = 39,321,600
  constexpr size_t HL   = HH   + 39321600;
  constexpr size_t QB   = HH;                       // q fp32 (39,321,600) aliases dead H hi
  constexpr size_t KTB  = HL;                       // kT fp32 (9,830,400) aliases dead H lo
  constexpr size_t BITS = HL   + 10240000;          // 1,638,400
  constexpr size_t PH   = HL   + 39321600;          // mel proj hi 19,660,800
  constexpr size_t PL   = PH   + 19660800;          // ends ~163.9 MB

  float* out = (float*)d_out;
  float* o_attn = out;
  float* o_logp = out + (size_t)10240000;
  float* o_hard = out + (size_t)20480000;
  float* o_dur  = out + (size_t)30720000;

  hipMemsetAsync(o_hard, 0, (size_t)(10240000 + 6400) * sizeof(float), stream);

  // input splits (channel-padded)
  split_pad_k<<<9600, 256, 0, stream>>>(mel_x, (__bf16*)(wsb + MXH), (__bf16*)(wsb + MXL), 80, 96, 2457600L);
  split_pad_k<<<12800, 256, 0, stream>>>(txt_x, (__bf16*)(wsb + TXH), (__bf16*)(wsb + TXL), 512, 512, 3276800L);
  // weight repack+split
  wsplit_k<<<2880, 256, 0, stream>>>(mel_w1, (__bf16*)(wsb + W1MH), (__bf16*)(wsb + W1ML), 80, 5, 96, 737280L);
  wsplit_k<<<5760, 256, 0, stream>>>(mel_w2, (__bf16*)(wsb + W2MH), (__bf16*)(wsb + W2ML), 768, 5, 768, 1474560L);
  wsplit_k<<<9216, 256, 0, stream>>>(txt_w1, (__bf16*)(wsb + W1TH), (__bf16*)(wsb + W1TL), 512, 3, 512, 2359296L);
  wsplit_k<<<3456, 256, 0, stream>>>(txt_w2, (__bf16*)(wsb + W2TH), (__bf16*)(wsb + W2TL), 768, 3, 768, 884736L);
  wsplit_k<<<576, 256, 0, stream>>>(wq, (__bf16*)(wsb + WQH), (__bf16*)(wsb + WQL), 384, 1, 384, 147456L);
  wsplit_k<<<576, 256, 0, stream>>>(wk, (__bf16*)(wsb + WKH), (__bf16*)(wsb + WKL), 384, 1, 384, 147456L);

  // text pipeline (conv1 -> conv2 overwrites dead TXH/TXL region)
  conv1_mfma<512, 3, 400><<<dim3(4, 12, B), 256, 0, stream>>>(
      (const __bf16*)(wsb + TXH), (const __bf16*)(wsb + TXL),
      (const __bf16*)(wsb + W1TH), (const __bf16*)(wsb + W1TL),
      txt_b1, xl, (__bf16*)(wsb + HH), (__bf16*)(wsb + HL));
  conv2_mfma<768, 3, 400, true, true, false><<<dim3(4, 3, B), 256, 0, stream>>>(
      (const __bf16*)(wsb + HH), (const __bf16*)(wsb + HL),
      (const __bf16*)(wsb + W2TH), (const __bf16*)(wsb + W2TL),
      txt_b2, xl, nullptr, (__bf16*)(wsb + TPH), (__bf16*)(wsb + TPL));

  // mel pipeline
  conv1_mfma<96, 5, 1600><<<dim3(13, 12, B), 256, 0, stream>>>(
      (const __bf16*)(wsb + MXH), (const __bf16*)(wsb + MXL),
      (const __bf16*)(wsb + W1MH), (const __bf16*)(wsb + W1ML),
      mel_b1, yl, (__bf16*)(wsb + HH), (__bf16*)(wsb + HL));
  conv2_mfma<768, 5, 1600, true, true, false><<<dim3(13, 3, B), 256, 0, stream>>>(
      (const __bf16*)(wsb + HH), (const __bf16*)(wsb + HL),
      (const __bf16*)(wsb + W2MH), (const __bf16*)(wsb + W2ML),
      mel_b2, yl, nullptr, (__bf16*)(wsb + PH), (__bf16*)(wsb + PL));

  // q/k projections (MFMA, K=1) — H region now dead, holds q / kT
  conv2_mfma<384, 1, 400, false, false, true><<<dim3(4, 3, B), 256, 0, stream>>>(
      (const __bf16*)(wsb + TPH), (const __bf16*)(wsb + TPL),
      (const __bf16*)(wsb + WKH), (const __bf16*)(wsb + WKL),
      bk, xl, (float*)(wsb + KTB), nullptr, nullptr);
  conv2_mfma<384, 1, 1600, false, false, false><<<dim3(13, 3, B), 256, 0, stream>>>(
      (const __bf16*)(wsb + PH), (const __bf16*)(wsb + PL),
      (const __bf16*)(wsb + WQH), (const __bf16*)(wsb + WQL),
      bq, yl, (float*)(wsb + QB), nullptr, nullptr);

  // attention + MAS
  scores_k<<<dim3(100, B), 512, 0, stream>>>(
      (const float*)(wsb + QB), (const float*)(wsb + KTB), xl, yl, o_attn, o_logp);
  mas_k<<<B, 64, 0, stream>>>(o_logp, xl, yl, (unsigned char*)(wsb + BITS), o_hard, o_dur);
}